// Round 8
// baseline (156.859 us; speedup 1.0000x reference)
//
#include <hip/hip_runtime.h>

#define MAXIT  100
#define TARGET 30.0f
#define WEIGHT 0.1f
#define EPS    1e-6f
#define EPB    1024    // elements per block
#define TPB    256
#define R0     12      // phase-A iters (3 bodies of 4, from z=0)
#define RSTEP  12      // iters per queue round (3 bodies of 4)
#define ND_INSET ((100.0f - TARGET) * (1.0f / TARGET))

// Four Mandelbrot iterations with DEFERRED escape check (tested once, at the
// 4th step). Soundness: entering mag <= 4 and |c| <= 2 for any orbit that
// reaches here (|c| > 2 escapes at iter 1 = body4 #1 step 1, where growth is
// also monotone); once mag_j > 4, |z_{j+1}| >= mag_j - |c| > sqrt(mag_j), so
// mag grows monotonically and m4 > 4 catches any in-body escape. The exact
// escape step is decoded in the rare retire path from live intermediates.
// Cycle check once per body4 (convergent orbits stay below EPS once there;
// delayed detection records the identical value 100). Precedence matches the
// reference: earlier escape > cycle-at-step-4 > escape-at-step-4.
__device__ __forceinline__ void body4(float& zr, float& zi, float cr, float ci,
                                      float fb, float& nd, bool& alive) {
  float t0  = __builtin_fmaf(-zi, zi, cr);
  float zr1 = __builtin_fmaf(zr, zr, t0);
  float zi1 = __builtin_fmaf(zr + zr, zi, ci);

  float t1  = __builtin_fmaf(-zi1, zi1, cr);
  float zr2 = __builtin_fmaf(zr1, zr1, t1);
  float zi2 = __builtin_fmaf(zr1 + zr1, zi1, ci);

  float t2  = __builtin_fmaf(-zi2, zi2, cr);
  float zr3 = __builtin_fmaf(zr2, zr2, t2);
  float zi3 = __builtin_fmaf(zr2 + zr2, zi2, ci);

  float t3  = __builtin_fmaf(-zi3, zi3, cr);
  float zr4 = __builtin_fmaf(zr3, zr3, t3);
  float zi4 = __builtin_fmaf(zr3 + zr3, zi3, ci);

  float m4  = __builtin_fmaf(zr4, zr4, zi4 * zi4);
  bool  cyc = (fabsf(zr4 - zr3) < EPS) & (fabsf(zi4 - zi3) < EPS);
  bool  e4  = m4 > 4.0f;
  zr = zr4; zi = zi4;

  if ((e4 | cyc) & alive) {                  // rare path: retire + decode
    bool e1 = __builtin_fmaf(zr1, zr1, zi1 * zi1) > 4.0f;
    bool e2 = __builtin_fmaf(zr2, zr2, zi2 * zi2) > 4.0f;
    bool e3 = __builtin_fmaf(zr3, zr3, zi3 * zi3) > 4.0f;
    float f = 100.0f;                        // cycle (incl. cycle-beats-e4)
    if (e4 & !cyc) f = fb + 4.0f;
    if (e3) f = fb + 3.0f;
    if (e2) f = fb + 2.0f;
    if (e1) f = fb + 1.0f;
    f = fminf(f, 100.0f);                    // last-round overshoot clamp
    nd += fabsf(f - TARGET) * (1.0f / TARGET);
    alive = false;
  }
}

// Closed-form bounded-orbit test: main cardioid + period-2 bulb.
// For these c the reference provably outputs exactly 100.0.
__device__ __forceinline__ bool inside_main_regions(float cr, float ci) {
  float ci2 = ci * ci;
  float xq  = cr - 0.25f;
  float q   = __builtin_fmaf(xq, xq, ci2);
  bool card = q * (q + xq) < 0.25f * ci2;
  float xb  = cr + 1.0f;
  bool bulb = __builtin_fmaf(xb, xb, ci2) < 0.0625f;
  return card | bulb;
}

__global__ __launch_bounds__(TPB) void escape_partial(
    const float* __restrict__ crg, const float* __restrict__ cig,
    float* __restrict__ partial, int n) {
  __shared__ float4 q[EPB];
  __shared__ int scount;
  __shared__ float sm[4];

  const int tid  = threadIdx.x;
  const int lane = tid & 63;
  const int wid  = tid >> 6;
  const int blockBase = blockIdx.x * EPB;

  float nd = 0.0f;
  float eZr[4], eZi[4], eCr[4], eCi[4];
  bool  eAl[4];

  // ---- phase A: iters 1..R0 from z=0, float4 global loads ----
  const bool fullBlock = (blockBase + EPB) <= n;
  float4 vcr, vci;
  if (fullBlock) {
    vcr = reinterpret_cast<const float4*>(crg + blockBase)[tid];
    vci = reinterpret_cast<const float4*>(cig + blockBase)[tid];
  } else {
    int b = blockBase + 4 * tid;
    vcr.x = (b + 0 < n) ? crg[b + 0] : 9.0f;  vci.x = (b + 0 < n) ? cig[b + 0] : 9.0f;
    vcr.y = (b + 1 < n) ? crg[b + 1] : 9.0f;  vci.y = (b + 1 < n) ? cig[b + 1] : 9.0f;
    vcr.z = (b + 2 < n) ? crg[b + 2] : 9.0f;  vci.z = (b + 2 < n) ? cig[b + 2] : 9.0f;
    vcr.w = (b + 3 < n) ? crg[b + 3] : 9.0f;  vci.w = (b + 3 < n) ? cig[b + 3] : 9.0f;
  }
  const float crs[4] = {vcr.x, vcr.y, vcr.z, vcr.w};
  const float cis[4] = {vci.x, vci.y, vci.z, vci.w};
  const bool  vld[4] = {
    fullBlock || (blockBase + 4 * tid + 0 < n),
    fullBlock || (blockBase + 4 * tid + 1 < n),
    fullBlock || (blockBase + 4 * tid + 2 < n),
    fullBlock || (blockBase + 4 * tid + 3 < n)};

  #pragma unroll
  for (int k = 0; k < 4; ++k) {
    float c_r = crs[k], c_i = cis[k];
    bool inside = inside_main_regions(c_r, c_i) & vld[k];
    if (inside) nd += ND_INSET;            // provably iters == 100
    float zr = 0.0f, zi = 0.0f;            // body4 from z=0 reproduces z1=c
    bool alive = vld[k] & (!inside);
    body4(zr, zi, c_r, c_i, 0.0f, nd, alive);
    body4(zr, zi, c_r, c_i, 4.0f, nd, alive);
    body4(zr, zi, c_r, c_i, 8.0f, nd, alive);
    eAl[k] = alive; eZr[k] = zr; eZi[k] = zi; eCr[k] = c_r; eCi[k] = c_i;
  }

  if (tid == 0) scount = 0;
  __syncthreads();
  #pragma unroll
  for (int k = 0; k < 4; ++k) {            // ballot-compact append into LDS queue
    unsigned long long bal = __ballot(eAl[k]);
    int cnt = __popcll(bal);
    if (cnt) {
      int wbase = 0;
      if (lane == 0) wbase = atomicAdd(&scount, cnt);
      wbase = __shfl(wbase, 0, 64);
      if (eAl[k]) {
        int pos = wbase + __popcll(bal & ((1ull << lane) - 1ull));
        q[pos] = make_float4(eZr[k], eZi[k], eCr[k], eCi[k]);
      }
    }
  }
  __syncthreads();
  int S = scount;
  int rot = 0;

  // ---- queue rounds: base = 12,24,...,96 (last overshoots to 108; clamped) ----
  for (int base = R0; base < MAXIT && S > 0; base += RSTEP) {
    rot = (rot + 64) & (TPB - 1);          // rotate partial-wave tail across SIMDs
    const int effTid = (tid + rot) & (TPB - 1);
    const float fb = (float)base;
    #pragma unroll
    for (int k = 0; k < 4; ++k) {
      eAl[k] = false;
      int j = k * TPB + effTid;
      if (j < S) {
        float4 e = q[j];
        float zr = e.x, zi = e.y, c_r = e.z, c_i = e.w;
        bool alive = true;
        body4(zr, zi, c_r, c_i, fb, nd, alive);
        body4(zr, zi, c_r, c_i, fb + 4.0f, nd, alive);
        body4(zr, zi, c_r, c_i, fb + 8.0f, nd, alive);
        eAl[k] = alive; eZr[k] = zr; eZi[k] = zi; eCr[k] = c_r; eCi[k] = c_i;
      }
    }
    __syncthreads();                       // all queue reads done
    if (tid == 0) scount = 0;
    __syncthreads();
    #pragma unroll
    for (int k = 0; k < 4; ++k) {          // in-place re-compaction
      unsigned long long bal = __ballot(eAl[k]);
      int cnt = __popcll(bal);
      if (cnt) {
        int wbase = 0;
        if (lane == 0) wbase = atomicAdd(&scount, cnt);
        wbase = __shfl(wbase, 0, 64);
        if (eAl[k]) {
          int pos = wbase + __popcll(bal & ((1ull << lane) - 1ull));
          q[pos] = make_float4(eZr[k], eZi[k], eCr[k], eCi[k]);
        }
      }
    }
    __syncthreads();
    S = scount;
  }

  // ---- survivors (ran to >=100 without escape/cycle): iters = 100 ----
  {
    int mine = 0;
    #pragma unroll
    for (int k = 0; k < 4; ++k) if (k * TPB + tid < S) ++mine;
    nd += (float)mine * ND_INSET;
  }

  // ---- block reduce ----
  for (int off = 32; off > 0; off >>= 1) nd += __shfl_down(nd, off, 64);
  if (lane == 0) sm[wid] = nd;
  __syncthreads();
  if (tid == 0) partial[blockIdx.x] = sm[0] + sm[1] + sm[2] + sm[3];
}

// Single block, float4 reads of the partials.
__global__ __launch_bounds__(256) void reduce_final(
    const float* __restrict__ partial, int nparts,
    float* __restrict__ out, float scale) {
  float s = 0.0f;
  int n4 = nparts >> 2;
  const float4* p4 = reinterpret_cast<const float4*>(partial);
  for (int i = threadIdx.x; i < n4; i += 256) {
    float4 v = p4[i];
    s += (v.x + v.y) + (v.z + v.w);
  }
  for (int i = (n4 << 2) + threadIdx.x; i < nparts; i += 256) s += partial[i];
  for (int off = 32; off > 0; off >>= 1) s += __shfl_down(s, off, 64);
  __shared__ float sm[4];
  int lane = threadIdx.x & 63, wid = threadIdx.x >> 6;
  if (lane == 0) sm[wid] = s;
  __syncthreads();
  if (threadIdx.x == 0)
    out[0] = (sm[0] + sm[1] + sm[2] + sm[3]) * scale;
}

extern "C" void kernel_launch(void* const* d_in, const int* in_sizes, int n_in,
                              void* d_out, int out_size, void* d_ws, size_t ws_size,
                              hipStream_t stream) {
  const float* cr = (const float*)d_in[0];
  const float* ci = (const float*)d_in[1];
  int n = in_sizes[0];
  int blocks = (n + EPB - 1) / EPB;        // 8192 at N=8388608
  float* partial = (float*)d_ws;

  escape_partial<<<blocks, TPB, 0, stream>>>(cr, ci, partial, n);
  reduce_final<<<1, 256, 0, stream>>>(partial, blocks, (float*)d_out,
                                      WEIGHT / (float)n);
}